// Round 7
// baseline (131.572 us; speedup 1.0000x reference)
//
#include <hip/hip_runtime.h>
#include <stdint.h>

typedef float    f32x4  __attribute__((ext_vector_type(4)));
typedef __bf16   bf16x8 __attribute__((ext_vector_type(8)));
typedef uint32_t u32x4  __attribute__((ext_vector_type(4)));
typedef unsigned short u16x4 __attribute__((ext_vector_type(4)));

#define AS1 __attribute__((address_space(1)))
#define AS3 __attribute__((address_space(3)))

__device__ __forceinline__ unsigned short f2bf_bits(float f) {
  uint32_t u = __builtin_bit_cast(uint32_t, f);
  u += 0x7fffu + ((u >> 16) & 1u);      // RNE to bf16
  return (unsigned short)(u >> 16);
}

// ---------------- kernel 0: At[col][k] (bf16) = A[k][col] ----------------
// A: [256][1024] f32  ->  At: [1024][256] bf16 (in d_ws)
__global__ void k_transpose_cvt(const float* __restrict__ A,
                                unsigned short* __restrict__ At) {
  int n = blockIdx.x * blockDim.x + threadIdx.x;  // 65536 threads
  int o = n << 2;                                 // 4 elements per thread
  int col = o >> 8;
  int k   = o & 255;
  u16x4 v;
#pragma unroll
  for (int j = 0; j < 4; ++j) v[j] = f2bf_bits(A[(size_t)(k + j) * 1024 + col]);
  *reinterpret_cast<u16x4*>(At + o) = v;          // coalesced write
}

// ---------------- kernel 1: block-specialized fill + GEMM ----------------
// Grid 2048, parity-interleaved: odd blocks = compute (group b>>1), even =
// fill (group b>>1). Fill blocks stream zeros to the 15/16 of each row's
// 64B lines that hold no diagonal entry (pure-store waves, no barriers).
// Compute blocks: BM=64 GEMM (no in-loop global stores), then write the 256
// diagonal-containing lines (15 zeros + 1 value each). Line sets are
// disjoint -> no inter-block ordering; every out byte written every call.
// Per row r: diag line dl(r) = ((r&127)>>4) + (r<128 ? 8 : 0), float slot
// within line = r&15.  (row i<128: col 128+i; row 128+i: col i.)
__launch_bounds__(256, 4)
__global__ void k_main(const float* __restrict__ x,
                       const unsigned short* __restrict__ At,
                       float* __restrict__ out) {
  __shared__ alignas(16) char lds[4][8192];

  const int b   = blockIdx.x;
  const int tid = threadIdx.x;
  const int g   = b >> 1;
  float* og = out + (size_t)g * 65536;           // group's 256KB slab

  if (!(b & 1)) {
    // ---------------- fill block: zero non-diag lines of group g ----------
    const int w = tid >> 6;            // wave 0..3
    const int l = (tid >> 2) & 15;     // line within row, 0..15
    const int q = tid & 3;             // 16B quarter within line
    const f32x4 z4 = {0.f, 0.f, 0.f, 0.f};
    // wave handles one full row (1KB) per iter; skip is wave-uniform quad mask
    for (int i = 0; i < 64; ++i) {
      int r  = i * 4 + w;                               // 0..255
      int dl = ((r & 127) >> 4) + (r < 128 ? 8 : 0);
      if (l != dl)
        __builtin_nontemporal_store(
            z4, reinterpret_cast<f32x4*>(og + r * 256 + l * 16 + q * 4));
    }
    return;
  }

  // ---------------- compute block: GEMM + silu rowsum + diag lines --------
  const int lane = tid & 63;
  const int w    = tid >> 6;          // wave 0..3
  const int brow = g * 64;

  const int col = lane & 15;          // A-frag row / B-frag col / C col
  const int hi  = lane >> 4;          // k-subblock select

  // staging: LDS linear chunk p (16B) <- global byte (p ^ swz(p)); swz is an
  // involution on bits 4..6 keyed by bits 9..11 -> conflict-free b128 reads.
  uint32_t p0  = (uint32_t)(w * 2048 + lane * 16);
  uint32_t so0 = p0 ^ (((p0 >> 9) & 7u) << 4);
  uint32_t p1  = p0 + 1024u;
  uint32_t so1 = p1 ^ (((p1 >> 9) & 7u) << 4);

  // prefetch tiles 0,1 into buffers 0,1 (complete during x-load phase)
  {
    const char* t0 = (const char*)At;
    const char* t1 = (const char*)At + 8192;
    __builtin_amdgcn_global_load_lds((const AS1 uint32_t*)(t0 + so0),
                                     (AS3 uint32_t*)(lds[0] + w * 2048), 16, 0, 0);
    __builtin_amdgcn_global_load_lds((const AS1 uint32_t*)(t0 + so1),
                                     (AS3 uint32_t*)(lds[0] + w * 2048 + 1024), 16, 0, 0);
    __builtin_amdgcn_global_load_lds((const AS1 uint32_t*)(t1 + so0),
                                     (AS3 uint32_t*)(lds[1] + w * 2048), 16, 0, 0);
    __builtin_amdgcn_global_load_lds((const AS1 uint32_t*)(t1 + so1),
                                     (AS3 uint32_t*)(lds[1] + w * 2048 + 1024), 16, 0, 0);
  }
  __builtin_amdgcn_sched_barrier(0);   // keep x loads below the prefetches

  // x fragments: row = brow + w*16 + col, k = s*32 + hi*8 + 0..7
  bf16x8 xf[8];
  {
    const float* xr = x + (size_t)(brow + w * 16 + col) * 256;
#pragma unroll
    for (int s = 0; s < 8; ++s) {
      f32x4 a = __builtin_nontemporal_load(
          reinterpret_cast<const f32x4*>(xr + s * 32 + hi * 8));
      f32x4 bq = __builtin_nontemporal_load(
          reinterpret_cast<const f32x4*>(xr + s * 32 + hi * 8 + 4));
      bf16x8 f;
      f[0] = (__bf16)a[0];  f[1] = (__bf16)a[1];
      f[2] = (__bf16)a[2];  f[3] = (__bf16)a[3];
      f[4] = (__bf16)bq[0]; f[5] = (__bf16)bq[1];
      f[6] = (__bf16)bq[2]; f[7] = (__bf16)bq[3];
      xf[s] = f;
    }
  }
  // drain prologue -> loop's counted vmcnt sees only loop ops
  asm volatile("s_waitcnt vmcnt(0)" ::: "memory");

  // B-frag read base: element (col, k= s*32+hi*8) -> byte col*512+s*64+hi*16,
  // XOR (col&7)<<4.  Disjoint bit fields -> addr(s) = rbase ^ (s<<6).
  uint32_t rbase = ((uint32_t)(col * 512 + hi * 16)) ^ ((uint32_t)(col & 7) << 4);

  float sums[4] = {0.f, 0.f, 0.f, 0.f};

  for (int tile = 0; tile < 64; ++tile) {
    // prefetch tile+2 (wrapped: uniform per-iter vmem pattern, 2 loads/iter)
    {
      int pt = (tile + 2) & 63;
      const char* tsrc = (const char*)At + (size_t)pt * 8192;
      char* dst = lds[(tile + 2) & 3] + w * 2048;
      __builtin_amdgcn_global_load_lds((const AS1 uint32_t*)(tsrc + so0),
                                       (AS3 uint32_t*)dst, 16, 0, 0);
      __builtin_amdgcn_global_load_lds((const AS1 uint32_t*)(tsrc + so1),
                                       (AS3 uint32_t*)(dst + 1024), 16, 0, 0);
    }
    // wait for tile's 2 loads (issued 2 iters ago): younger = 2(t-1)+2(t)=4
    asm volatile("s_waitcnt vmcnt(4)\n\ts_barrier" ::: "memory");

    const char* buf = lds[tile & 3];
    bf16x8 bfr[8];
#pragma unroll
    for (int s = 0; s < 8; ++s) {
      uint32_t addr = rbase ^ ((uint32_t)s << 6);
      bfr[s] = __builtin_bit_cast(
          bf16x8, *reinterpret_cast<const u32x4*>(buf + addr));
    }
    f32x4 acc = {0.f, 0.f, 0.f, 0.f};
#pragma unroll
    for (int s = 0; s < 8; ++s)
      acc = __builtin_amdgcn_mfma_f32_16x16x32_bf16(xf[s], bfr[s], acc, 0, 0, 0);
#pragma unroll
    for (int j = 0; j < 4; ++j) {
      float z = acc[j];
      float sig = __builtin_amdgcn_rcpf(1.0f + __expf(-z));
      sums[j] += z * sig;
    }
    // 4 buffers -> next write to this buffer lands 2 barriers later: no WAR.
  }

  // reduce over the 16 column-lanes (C layout: col = lane&15)
#pragma unroll
  for (int j = 0; j < 4; ++j) {
    float v = sums[j];
    v += __shfl_xor(v, 1, 64);
    v += __shfl_xor(v, 2, 64);
    v += __shfl_xor(v, 4, 64);
    v += __shfl_xor(v, 8, 64);
    sums[j] = v;
  }

  // stage the 64 per-row sums in LDS, then all 256 threads write diag lines
  float* sarr = reinterpret_cast<float*>(lds);
  __syncthreads();                      // all waves done with LDS buffers
  if (col == 0) {
#pragma unroll
    for (int j = 0; j < 4; ++j) sarr[w * 16 + hi * 4 + j] = sums[j];
  }
  __syncthreads();
  {
    int r  = tid;                       // output row 0..255
    int c  = (r & 127) >> 1;            // x-row within group
    float s = sarr[c];
    s = (r < 128) ? s : -s;
    int dl = ((r & 127) >> 4) + (r < 128 ? 8 : 0);
    int p  = r & 15;                    // float slot within the 64B line
    float* lp = og + r * 256 + dl * 16;
#pragma unroll
    for (int q2 = 0; q2 < 4; ++q2) {
      f32x4 v = {0.f, 0.f, 0.f, 0.f};
      if ((p >> 2) == q2) {
        v[0] = ((p & 3) == 0) ? s : 0.f;
        v[1] = ((p & 3) == 1) ? s : 0.f;
        v[2] = ((p & 3) == 2) ? s : 0.f;
        v[3] = ((p & 3) == 3) ? s : 0.f;
      }
      __builtin_nontemporal_store(v, reinterpret_cast<f32x4*>(lp + q2 * 4));
    }
  }
}

extern "C" void kernel_launch(void* const* d_in, const int* in_sizes, int n_in,
                              void* d_out, int out_size, void* d_ws, size_t ws_size,
                              hipStream_t stream) {
  const float* x = (const float*)d_in[0];   // [65536, 256]
  const float* A = (const float*)d_in[1];   // [256, 1024]
  float* out = (float*)d_out;               // [1024, 256, 256]
  unsigned short* At = (unsigned short*)d_ws;  // 512 KB bf16 transposed weights

  k_transpose_cvt<<<256, 256, 0, stream>>>(A, At);
  k_main<<<2048, 256, 0, stream>>>(x, At, out);
}

// Round 8
// 97.538 us; speedup vs baseline: 1.3489x; 1.3489x over previous
//
#include <hip/hip_runtime.h>
#include <stdint.h>

typedef float    f32x4  __attribute__((ext_vector_type(4)));
typedef __bf16   bf16x8 __attribute__((ext_vector_type(8)));
typedef uint32_t u32x4  __attribute__((ext_vector_type(4)));
typedef unsigned short u16x4 __attribute__((ext_vector_type(4)));

#define AS1 __attribute__((address_space(1)))
#define AS3 __attribute__((address_space(3)))

__device__ __forceinline__ unsigned short f2bf_bits(float f) {
  uint32_t u = __builtin_bit_cast(uint32_t, f);
  u += 0x7fffu + ((u >> 16) & 1u);      // RNE to bf16
  return (unsigned short)(u >> 16);
}

// ---------------- kernel 0: At[col][k] (bf16) = A[k][col] ----------------
// A: [256][1024] f32  ->  At: [1024][256] bf16 (in d_ws)
__global__ void k_transpose_cvt(const float* __restrict__ A,
                                unsigned short* __restrict__ At) {
  int n = blockIdx.x * blockDim.x + threadIdx.x;  // 65536 threads
  int o = n << 2;                                 // 4 elements per thread
  int col = o >> 8;
  int k   = o & 255;
  u16x4 v;
#pragma unroll
  for (int j = 0; j < 4; ++j) v[j] = f2bf_bits(A[(size_t)(k + j) * 1024 + col]);
  *reinterpret_cast<u16x4*>(At + o) = v;          // coalesced write
}

// ---------------- kernel 1: GEMM + silu rowsum -> j12 (NO big stores) ----
// x: [65536][256] f32, At: [1024][256] bf16, j12: [1024][64] f32 (ws)
// 1024 blocks (one group each) x 256 threads (4 waves). BM=64.
// 4 LDS buffers, 2-tile prefetch via global_load_lds, counted vmcnt(4),
// one s_barrier per tile. Two independent MFMA acc chains per tile.
__launch_bounds__(256, 4)
__global__ void k_gemm_sums(const float* __restrict__ x,
                            const unsigned short* __restrict__ At,
                            float* __restrict__ j12) {
  __shared__ alignas(16) char lds[4][8192];

  const int tid  = threadIdx.x;
  const int lane = tid & 63;
  const int w    = tid >> 6;          // wave 0..3
  const int g    = blockIdx.x;        // group
  const int brow = g * 64;

  const int col = lane & 15;          // A-frag row / B-frag col / C col
  const int hi  = lane >> 4;          // k-subblock select

  // staging: LDS linear chunk p (16B) <- global byte (p ^ swz(p)); swz is an
  // involution on bits 4..6 keyed by bits 9..11 -> conflict-free b128 reads.
  uint32_t p0  = (uint32_t)(w * 2048 + lane * 16);
  uint32_t so0 = p0 ^ (((p0 >> 9) & 7u) << 4);
  uint32_t p1  = p0 + 1024u;
  uint32_t so1 = p1 ^ (((p1 >> 9) & 7u) << 4);

  // prefetch tiles 0,1 into buffers 0,1 (complete during x-load phase)
  {
    const char* t0 = (const char*)At;
    const char* t1 = (const char*)At + 8192;
    __builtin_amdgcn_global_load_lds((const AS1 uint32_t*)(t0 + so0),
                                     (AS3 uint32_t*)(lds[0] + w * 2048), 16, 0, 0);
    __builtin_amdgcn_global_load_lds((const AS1 uint32_t*)(t0 + so1),
                                     (AS3 uint32_t*)(lds[0] + w * 2048 + 1024), 16, 0, 0);
    __builtin_amdgcn_global_load_lds((const AS1 uint32_t*)(t1 + so0),
                                     (AS3 uint32_t*)(lds[1] + w * 2048), 16, 0, 0);
    __builtin_amdgcn_global_load_lds((const AS1 uint32_t*)(t1 + so1),
                                     (AS3 uint32_t*)(lds[1] + w * 2048 + 1024), 16, 0, 0);
  }
  __builtin_amdgcn_sched_barrier(0);   // keep x loads below the prefetches

  // x fragments: row = brow + w*16 + col, k = s*32 + hi*8 + 0..7
  bf16x8 xf[8];
  {
    const float* xr = x + (size_t)(brow + w * 16 + col) * 256;
#pragma unroll
    for (int s = 0; s < 8; ++s) {
      f32x4 a = __builtin_nontemporal_load(
          reinterpret_cast<const f32x4*>(xr + s * 32 + hi * 8));
      f32x4 bq = __builtin_nontemporal_load(
          reinterpret_cast<const f32x4*>(xr + s * 32 + hi * 8 + 4));
      bf16x8 f;
      f[0] = (__bf16)a[0];  f[1] = (__bf16)a[1];
      f[2] = (__bf16)a[2];  f[3] = (__bf16)a[3];
      f[4] = (__bf16)bq[0]; f[5] = (__bf16)bq[1];
      f[6] = (__bf16)bq[2]; f[7] = (__bf16)bq[3];
      xf[s] = f;
    }
  }
  // drain prologue -> loop's counted vmcnt sees only loop ops
  asm volatile("s_waitcnt vmcnt(0)" ::: "memory");

  // B-frag read base: element (col, k= s*32+hi*8) -> byte col*512+s*64+hi*16,
  // XOR (col&7)<<4.  Disjoint bit fields -> addr(s) = rbase ^ (s<<6).
  uint32_t rbase = ((uint32_t)(col * 512 + hi * 16)) ^ ((uint32_t)(col & 7) << 4);

  float sums[4] = {0.f, 0.f, 0.f, 0.f};

  for (int tile = 0; tile < 64; ++tile) {
    // prefetch tile+2 (wrapped: uniform 2-loads-per-iter vmem pattern)
    {
      int pt = (tile + 2) & 63;
      const char* tsrc = (const char*)At + (size_t)pt * 8192;
      char* dst = lds[(tile + 2) & 3] + w * 2048;
      __builtin_amdgcn_global_load_lds((const AS1 uint32_t*)(tsrc + so0),
                                       (AS3 uint32_t*)dst, 16, 0, 0);
      __builtin_amdgcn_global_load_lds((const AS1 uint32_t*)(tsrc + so1),
                                       (AS3 uint32_t*)(dst + 1024), 16, 0, 0);
    }
    // wait for this tile's 2 loads (issued 2 iters ago):
    // younger = 2 (iter t-1) + 2 (iter t) = 4 -> vmcnt(4)
    asm volatile("s_waitcnt vmcnt(4)\n\ts_barrier" ::: "memory");

    const char* buf = lds[tile & 3];
    bf16x8 bfr[8];
#pragma unroll
    for (int s = 0; s < 8; ++s) {
      uint32_t addr = rbase ^ ((uint32_t)s << 6);
      bfr[s] = __builtin_bit_cast(
          bf16x8, *reinterpret_cast<const u32x4*>(buf + addr));
    }
    // two independent acc chains (halved MFMA dependency latency)
    f32x4 acc0 = {0.f, 0.f, 0.f, 0.f};
    f32x4 acc1 = {0.f, 0.f, 0.f, 0.f};
#pragma unroll
    for (int s = 0; s < 4; ++s) {
      acc0 = __builtin_amdgcn_mfma_f32_16x16x32_bf16(xf[s],     bfr[s],     acc0, 0, 0, 0);
      acc1 = __builtin_amdgcn_mfma_f32_16x16x32_bf16(xf[s + 4], bfr[s + 4], acc1, 0, 0, 0);
    }
#pragma unroll
    for (int j = 0; j < 4; ++j) {
      float z = acc0[j] + acc1[j];
      float sig = __builtin_amdgcn_rcpf(1.0f + __expf(-z));
      sums[j] += z * sig;
    }
    // 4 buffers -> next write to this buffer lands 2 barriers later: no WAR.
  }

  // reduce over the 16 column-lanes (C layout: col = lane&15)
#pragma unroll
  for (int j = 0; j < 4; ++j) {
    float v = sums[j];
    v += __shfl_xor(v, 1, 64);
    v += __shfl_xor(v, 2, 64);
    v += __shfl_xor(v, 4, 64);
    v += __shfl_xor(v, 8, 64);
    sums[j] = v;
  }

  // j12[g][c], c = x-row within group (sign applied by the fill kernel)
  if (col == 0) {
#pragma unroll
    for (int j = 0; j < 4; ++j)
      j12[g * 64 + w * 16 + hi * 4 + j] = sums[j];
  }
}

// ---------------- kernel 2: contiguous fill with embedded diagonals ------
// out: [1024][256][256] f32. 2048 blocks x 256 threads; each block streams a
// contiguous 128KB chunk (32 iters x 4KB) of plain float4 stores — identical
// pattern to the 6.9 TB/s fill — with the diagonal value substituted
// branchlessly where the stream crosses it. j12 reads are L2-resident.
__launch_bounds__(256, 8)
__global__ void k_fill_diag(const float* __restrict__ j12,
                            float* __restrict__ out) {
  const int tid = threadIdx.x;
  const size_t base = (size_t)blockIdx.x * 32768;   // floats
#pragma unroll 2
  for (int i = 0; i < 32; ++i) {
    size_t o = base + (size_t)i * 1024 + (tid << 2);
    int gf = (int)(o & 65535);          // float index within group slab
    int g  = (int)(o >> 16);
    int rr = gf >> 8;                   // out row 0..255
    int cc = gf & 255;                  // first col of this 16B store
    int ii = rr & 127;
    int dc = (rr < 128) ? (ii + 128) : ii;   // diag col for this row
    float s = 0.f;
    if ((dc >> 2) == (cc >> 2)) {       // our 16B holds the diagonal
      s = j12[g * 64 + (ii >> 1)];
      if (rr >= 128) s = -s;
    }
    int sl = dc & 3;
    f32x4 v;
    v[0] = (sl == 0) ? s : 0.f;
    v[1] = (sl == 1) ? s : 0.f;
    v[2] = (sl == 2) ? s : 0.f;
    v[3] = (sl == 3) ? s : 0.f;
    *reinterpret_cast<f32x4*>(out + o) = v;
  }
}

extern "C" void kernel_launch(void* const* d_in, const int* in_sizes, int n_in,
                              void* d_out, int out_size, void* d_ws, size_t ws_size,
                              hipStream_t stream) {
  const float* x = (const float*)d_in[0];   // [65536, 256]
  const float* A = (const float*)d_in[1];   // [256, 1024]
  float* out = (float*)d_out;               // [1024, 256, 256]
  unsigned short* At = (unsigned short*)d_ws;            // 512 KB bf16
  float* j12 = (float*)((char*)d_ws + 512 * 1024);       // 256 KB f32

  k_transpose_cvt<<<256, 256, 0, stream>>>(A, At);
  k_gemm_sums<<<1024, 256, 0, stream>>>(x, At, j12);
  k_fill_diag<<<2048, 256, 0, stream>>>(j12, out);
}

// Round 9
// 77.862 us; speedup vs baseline: 1.6898x; 1.2527x over previous
//
#include <hip/hip_runtime.h>
#include <stdint.h>

typedef float    f32x4  __attribute__((ext_vector_type(4)));
typedef __bf16   bf16x8 __attribute__((ext_vector_type(8)));
typedef uint32_t u32x4  __attribute__((ext_vector_type(4)));
typedef unsigned short u16x4 __attribute__((ext_vector_type(4)));

#define AS1 __attribute__((address_space(1)))
#define AS3 __attribute__((address_space(3)))

__device__ __forceinline__ unsigned short f2bf_bits(float f) {
  uint32_t u = __builtin_bit_cast(uint32_t, f);
  u += 0x7fffu + ((u >> 16) & 1u);      // RNE to bf16
  return (unsigned short)(u >> 16);
}

// ---------------- kernel 0: At[col][k] (bf16) = A[k][col] ----------------
// A: [256][1024] f32  ->  At: [1024][256] bf16 (in d_ws)
__global__ void k_transpose_cvt(const float* __restrict__ A,
                                unsigned short* __restrict__ At) {
  int n = blockIdx.x * blockDim.x + threadIdx.x;  // 65536 threads
  int o = n << 2;                                 // 4 elements per thread
  int col = o >> 8;
  int k   = o & 255;
  u16x4 v;
#pragma unroll
  for (int j = 0; j < 4; ++j) v[j] = f2bf_bits(A[(size_t)(k + j) * 1024 + col]);
  *reinterpret_cast<u16x4*>(At + o) = v;          // coalesced write
}

// ---------------- kernel 1: barrier-free fused GEMM + fill + diag --------
// 256 blocks x 256 threads. Wave w exclusively owns group g = bIdx*4+w:
//  - GEMM: 64 x-rows as 4 MFMA row-groups sharing each B-fragment read
//    (4x LDS-read amortization vs 1 rg/wave)
//  - B-tiles staged into WAVE-PRIVATE LDS buffers (4 x 8KB per wave),
//    3-deep prefetch, synced only by this wave's counted vmcnt — NO barriers
//  - fused zero-fill: 4KB contiguous (4 full out-rows) per tile
//  - epilogue: own vmcnt(0), shfl-reduce, write 256 diag entries (same-wave
//    ordering after drain -> race-free)
__launch_bounds__(256, 1)
__global__ void k_fused(const float* __restrict__ x,
                        const unsigned short* __restrict__ At,
                        float* __restrict__ out) {
  __shared__ alignas(16) char lds[4][4][8192];   // [wave][buf][8KB tile]

  const int tid  = threadIdx.x;
  const int lane = tid & 63;
  const int w    = tid >> 6;            // wave 0..3
  const int g    = blockIdx.x * 4 + w;  // this wave's group (0..1023)

  const int col = lane & 15;            // A row / B col / C col
  const int hi  = lane >> 4;            // k-subblock select

  // staging source offsets: LDS linear chunk p (16B) <- global (p ^ swz(p));
  // swz flips bits 4..6 keyed by bits 9..11 (col) -> conflict-free b128 reads
  uint32_t soff[8];
#pragma unroll
  for (int i = 0; i < 8; ++i) {
    uint32_t p = (uint32_t)(i * 1024 + lane * 16);
    soff[i] = p ^ (((p >> 9) & 7u) << 4);
  }

  // ---- prologue: prefetch tiles 0..2 into this wave's buffers 0..2 ------
#pragma unroll
  for (int t = 0; t < 3; ++t) {
    const char* src = (const char*)At + (size_t)t * 8192;
    char* dst = lds[w][t];
#pragma unroll
    for (int i = 0; i < 8; ++i)
      __builtin_amdgcn_global_load_lds((const AS1 uint32_t*)(src + soff[i]),
                                       (AS3 uint32_t*)(dst + i * 1024), 16, 0, 0);
  }
  __builtin_amdgcn_sched_barrier(0);   // keep x loads below the prefetches

  // ---- x fragments: rg r -> x-row g*64 + r*16 + col, k = s*32 + hi*8 ----
  bf16x8 xf[4][8];
#pragma unroll
  for (int r = 0; r < 4; ++r) {
    const float* xr = x + (size_t)(g * 64 + r * 16 + col) * 256;
#pragma unroll
    for (int s = 0; s < 8; ++s) {
      f32x4 a = __builtin_nontemporal_load(
          reinterpret_cast<const f32x4*>(xr + s * 32 + hi * 8));
      f32x4 bq = __builtin_nontemporal_load(
          reinterpret_cast<const f32x4*>(xr + s * 32 + hi * 8 + 4));
      bf16x8 f;
      f[0] = (__bf16)a[0];  f[1] = (__bf16)a[1];
      f[2] = (__bf16)a[2];  f[3] = (__bf16)a[3];
      f[4] = (__bf16)bq[0]; f[5] = (__bf16)bq[1];
      f[6] = (__bf16)bq[2]; f[7] = (__bf16)bq[3];
      xf[r][s] = f;
    }
  }
  // drain prologue -> loop's counted vmcnt sees only loop ops
  asm volatile("s_waitcnt vmcnt(0)" ::: "memory");

  // B-frag read: byte col*512 + s*64 + hi*16, XOR (col&7)<<4; disjoint bit
  // fields -> addr(s) = rbase ^ (s<<6)
  uint32_t rbase = ((uint32_t)(col * 512 + hi * 16)) ^ ((uint32_t)(col & 7) << 4);

  float sums[4][4] = {{0.f,0.f,0.f,0.f},{0.f,0.f,0.f,0.f},
                      {0.f,0.f,0.f,0.f},{0.f,0.f,0.f,0.f}};
  float* og = out + (size_t)g * 65536;   // wave's exclusive 256KB group slab
  const f32x4 z4 = {0.f, 0.f, 0.f, 0.f};

  for (int t = 0; t < 64; ++t) {
    // buf (t+3)&3's previous ds_reads (iter t-1) are consumed; make it explicit
    asm volatile("s_waitcnt lgkmcnt(0)" ::: "memory");
    // prefetch tile t+3 into this wave's buf (t+3)&3 (wrapped: uniform 12-op
    // per-iter vmem pattern keeps the vmcnt count exact every iteration)
    {
      int pt = (t + 3) & 63;
      const char* src = (const char*)At + (size_t)pt * 8192;
      char* dst = lds[w][(t + 3) & 3];
#pragma unroll
      for (int i = 0; i < 8; ++i)
        __builtin_amdgcn_global_load_lds((const AS1 uint32_t*)(src + soff[i]),
                                         (AS3 uint32_t*)(dst + i * 1024), 16, 0, 0);
    }
    __builtin_amdgcn_sched_barrier(0);   // pin [8L] before the stores
    // fused zero-fill: 4 contiguous out-rows (4KB) of own slab, no holes
    {
      float* zp = og + t * 1024 + lane * 4;
#pragma unroll
      for (int q = 0; q < 4; ++q)
        __builtin_nontemporal_store(z4, reinterpret_cast<f32x4*>(zp + q * 256));
    }
    // wait for THIS tile's 8 loads (issued 3 iters ago). Ops younger than the
    // last L(t): 4S(t-3) + 12(t-2) + 12(t-1) + 12(t) = 40 -> vmcnt(40).
    // ~40 outstanding vmem ops keep the write stream continuously fed.
    asm volatile("s_waitcnt vmcnt(40)" ::: "memory");

    const char* buf = lds[w][t & 3];
    bf16x8 bfr[8];
#pragma unroll
    for (int s = 0; s < 8; ++s) {
      uint32_t addr = rbase ^ ((uint32_t)s << 6);
      bfr[s] = __builtin_bit_cast(
          bf16x8, *reinterpret_cast<const u32x4*>(buf + addr));
    }
    // 4 independent MFMA chains (one per row-group) share each bfr[s]
    f32x4 acc[4] = {{0.f,0.f,0.f,0.f},{0.f,0.f,0.f,0.f},
                    {0.f,0.f,0.f,0.f},{0.f,0.f,0.f,0.f}};
#pragma unroll
    for (int s = 0; s < 8; ++s) {
#pragma unroll
      for (int r = 0; r < 4; ++r)
        acc[r] = __builtin_amdgcn_mfma_f32_16x16x32_bf16(xf[r][s], bfr[s],
                                                         acc[r], 0, 0, 0);
    }
#pragma unroll
    for (int r = 0; r < 4; ++r)
#pragma unroll
      for (int j = 0; j < 4; ++j) {
        float z = acc[r][j];
        float sig = __builtin_amdgcn_rcpf(1.0f + __expf(-z));
        sums[r][j] += z * sig;
      }
  }

  // drain own zero-stores; subsequent diag writes to the same lines are
  // same-wave ordered. No cross-wave/cross-block hazard (exclusive slab).
  asm volatile("s_waitcnt vmcnt(0)" ::: "memory");

  // reduce over the 16 column-lanes (C layout: col = lane&15)
#pragma unroll
  for (int r = 0; r < 4; ++r)
#pragma unroll
    for (int j = 0; j < 4; ++j) {
      float v = sums[r][j];
      v += __shfl_xor(v, 1, 64);
      v += __shfl_xor(v, 2, 64);
      v += __shfl_xor(v, 4, 64);
      v += __shfl_xor(v, 8, 64);
      sums[r][j] = v;
    }

  if (col == 0) {
#pragma unroll
    for (int r = 0; r < 4; ++r)
#pragma unroll
      for (int j = 0; j < 4; ++j) {
        int c = r * 16 + hi * 4 + j;     // x-row within group, 0..63
        float s = sums[r][j];
        og[(2 * c) * 256 + 128 + 2 * c]     =  s;   // out[g, i, 128+i], i=2c
        og[(2 * c + 1) * 256 + 129 + 2 * c] =  s;   // i=2c+1
        og[(128 + 2 * c) * 256 + 2 * c]     = -s;   // out[g, 128+i, i]
        og[(129 + 2 * c) * 256 + 2 * c + 1] = -s;
      }
  }
}

extern "C" void kernel_launch(void* const* d_in, const int* in_sizes, int n_in,
                              void* d_out, int out_size, void* d_ws, size_t ws_size,
                              hipStream_t stream) {
  const float* x = (const float*)d_in[0];   // [65536, 256]
  const float* A = (const float*)d_in[1];   // [256, 1024]
  float* out = (float*)d_out;               // [1024, 256, 256]
  unsigned short* At = (unsigned short*)d_ws;  // 512 KB bf16 transposed weights

  k_transpose_cvt<<<256, 256, 0, stream>>>(A, At);
  k_fused<<<256, 256, 0, stream>>>(x, At, out);
}